// Round 1
// baseline (61.068 us; speedup 1.0000x reference)
//
#include <hip/hip_runtime.h>

#define IMGD 28
#define OUTD 26
#define NCLS 10

// One image per lane. All lanes of a wave process the same output (r,c) at the
// same time, so W / conv_w / b addresses are wave-uniform (blockIdx/loop-counter
// only) -> compiler scalarizes them to s_load broadcasts.
// Image streamed through a rolling 3-row register buffer (A,Bv,C), all indices
// static after unrolling -> stays in VGPRs.

__global__ __launch_bounds__(64) void fused_conv_relu_fc(
    const float* __restrict__ x,      // [B, 784]
    const float* __restrict__ cw,     // [9]
    const float* __restrict__ Wp,     // [676, 10]
    const float* __restrict__ bp,     // [10]
    float* __restrict__ out,          // [B, 10]
    int B)
{
    const int img = blockIdx.x * 64 + threadIdx.x;
    if (img >= B) return;
    const float* __restrict__ xi = x + (size_t)img * (IMGD * IMGD);

    // conv kernel taps: uniform address -> scalar loads / SGPRs
    const float k00 = cw[0], k01 = cw[1], k02 = cw[2];
    const float k10 = cw[3], k11 = cw[4], k12 = cw[5];
    const float k20 = cw[6], k21 = cw[7], k22 = cw[8];

    float acc[NCLS];
#pragma unroll
    for (int j = 0; j < NCLS; ++j) acc[j] = bp[j];

    float A[IMGD], Bv[IMGD], C[IMGD];

    // load one 28-float image row as 7 float4 (16B-aligned: row stride 112B, img stride 3136B)
#define LOADROW(dst, r) do {                                            \
        const float4* __restrict__ p4 = (const float4*)(xi + (r) * IMGD); \
        _Pragma("unroll")                                               \
        for (int q = 0; q < 7; ++q) {                                   \
            float4 v = p4[q];                                           \
            (dst)[4*q+0] = v.x; (dst)[4*q+1] = v.y;                     \
            (dst)[4*q+2] = v.z; (dst)[4*q+3] = v.w;                     \
        }                                                               \
    } while (0)

    // one output row r from input rows X=r, Y=r+1, Z=r+2
#define ROWC(r, X, Y, Z) do {                                           \
        _Pragma("unroll")                                               \
        for (int c = 0; c < OUTD; ++c) {                                \
            float v = fmaf((X)[c+0], k00,                               \
                      fmaf((X)[c+1], k01,                               \
                      fmaf((X)[c+2], k02,                               \
                      fmaf((Y)[c+0], k10,                               \
                      fmaf((Y)[c+1], k11,                               \
                      fmaf((Y)[c+2], k12,                               \
                      fmaf((Z)[c+0], k20,                               \
                      fmaf((Z)[c+1], k21,                               \
                           (Z)[c+2] * k22))))))));                      \
            v = fmaxf(v, 0.0f);                                         \
            const float* __restrict__ wr = Wp + ((r) * OUTD + (c)) * NCLS; \
            _Pragma("unroll")                                           \
            for (int j = 0; j < NCLS; ++j)                              \
                acc[j] = fmaf(v, wr[j], acc[j]);                        \
        }                                                               \
    } while (0)

    LOADROW(A, 0);
    LOADROW(Bv, 1);
    LOADROW(C, 2);

    // rows 0..23, rotating the 3-row buffer; row t consumes rows t..t+2 and
    // prefetches row t+3 (used 3 full row-computations later).
    for (int tt = 0; tt < 8; ++tt) {
        const int r = 3 * tt;
        ROWC(r + 0, A, Bv, C);  LOADROW(A,  r + 3);
        ROWC(r + 1, Bv, C, A);  LOADROW(Bv, r + 4);
        ROWC(r + 2, C, A, Bv);  LOADROW(C,  r + 5);
    }
    ROWC(24, A, Bv, C);  LOADROW(A, 27);
    ROWC(25, Bv, C, A);

#undef LOADROW
#undef ROWC

    // 40B per image, 8B-aligned -> 5x float2 stores
    float2* __restrict__ o2 = (float2*)(out + (size_t)img * NCLS);
#pragma unroll
    for (int j = 0; j < 5; ++j)
        o2[j] = make_float2(acc[2*j], acc[2*j+1]);
}

extern "C" void kernel_launch(void* const* d_in, const int* in_sizes, int n_in,
                              void* d_out, int out_size, void* d_ws, size_t ws_size,
                              hipStream_t stream) {
    const float* x  = (const float*)d_in[0];
    const float* cw = (const float*)d_in[1];
    const float* Wp = (const float*)d_in[2];
    const float* bp = (const float*)d_in[3];
    float* out = (float*)d_out;

    const int B = in_sizes[0] / (IMGD * IMGD);   // 32768
    const int grid = (B + 63) / 64;              // 512 blocks x 1 wave

    fused_conv_relu_fc<<<grid, 64, 0, stream>>>(x, cw, Wp, bp, out, B);
}

// Round 2
// 43.137 us; speedup vs baseline: 1.4157x; 1.4157x over previous
//
#include <hip/hip_runtime.h>

#define IMGD 28
#define OUTD 26
#define NCLS 10
#define NW 8                   // row-split waves per 64-image group
#define THREADS (NW * 64)
#define LDSTRIDE 11            // pad 10 -> 11: lane stride 11 words, gcd(11,32)=1 -> 2-way (free)

// One image per lane; 8 waves share 64 images, each wave owns 3-4 output rows.
// W / conv_w addresses stay wave-uniform (r0 via readfirstlane) -> s_load
// broadcasts, no vector-memory traffic for weights. Per-lane image rows stream
// through a rolling 3-row register buffer, all statically indexed.

__global__ __launch_bounds__(THREADS, 4) void fused_conv_relu_fc(
    const float* __restrict__ x,      // [B, 784]
    const float* __restrict__ cw,     // [9]
    const float* __restrict__ Wp,     // [676, 10]
    const float* __restrict__ bp,     // [10]
    float* __restrict__ out,          // [B, 10]
    int B)
{
    __shared__ float part[NW * 64 * LDSTRIDE];

    const int lane = threadIdx.x & 63;
    const int w    = __builtin_amdgcn_readfirstlane((int)(threadIdx.x >> 6));
    const int img  = blockIdx.x * 64 + lane;

    // 26 rows = 2 waves x 4 + 6 waves x 3
    const int r0  = (w < 2) ? (w * 4) : (8 + (w - 2) * 3);
    const int cnt = (w < 2) ? 4 : 3;

    float acc[NCLS];
#pragma unroll
    for (int j = 0; j < NCLS; ++j) acc[j] = 0.0f;

    if (img < B) {
        const float* __restrict__ xi = x + (size_t)img * (IMGD * IMGD);

        const float k00 = cw[0], k01 = cw[1], k02 = cw[2];
        const float k10 = cw[3], k11 = cw[4], k12 = cw[5];
        const float k20 = cw[6], k21 = cw[7], k22 = cw[8];

        float A[IMGD], Bv[IMGD], C[IMGD];

#define LOADROW(dst, r) do {                                            \
        const float4* __restrict__ p4 = (const float4*)(xi + (r) * IMGD); \
        _Pragma("unroll")                                               \
        for (int q = 0; q < 7; ++q) {                                   \
            float4 v = p4[q];                                           \
            (dst)[4*q+0] = v.x; (dst)[4*q+1] = v.y;                     \
            (dst)[4*q+2] = v.z; (dst)[4*q+3] = v.w;                     \
        }                                                               \
    } while (0)

#define ROWC(r, X, Y, Z) do {                                           \
        const float* __restrict__ wrow = Wp + (size_t)(r) * (OUTD * NCLS); \
        _Pragma("unroll")                                               \
        for (int c = 0; c < OUTD; ++c) {                                \
            float v = fmaf((X)[c+0], k00,                               \
                      fmaf((X)[c+1], k01,                               \
                      fmaf((X)[c+2], k02,                               \
                      fmaf((Y)[c+0], k10,                               \
                      fmaf((Y)[c+1], k11,                               \
                      fmaf((Y)[c+2], k12,                               \
                      fmaf((Z)[c+0], k20,                               \
                      fmaf((Z)[c+1], k21,                               \
                           (Z)[c+2] * k22))))))));                      \
            v = fmaxf(v, 0.0f);                                         \
            _Pragma("unroll")                                           \
            for (int j = 0; j < NCLS; ++j)                              \
                acc[j] = fmaf(v, wrow[c * NCLS + j], acc[j]);           \
        }                                                               \
    } while (0)

        LOADROW(A,  r0 + 0);
        LOADROW(Bv, r0 + 1);
        LOADROW(C,  r0 + 2);

        ROWC(r0 + 0, A, Bv, C);   LOADROW(A,  r0 + 3);
        ROWC(r0 + 1, Bv, C, A);   LOADROW(Bv, r0 + 4);
        if (cnt == 4) {
            ROWC(r0 + 2, C, A, Bv);  LOADROW(C, r0 + 5);
            ROWC(r0 + 3, A, Bv, C);
        } else {
            ROWC(r0 + 2, C, A, Bv);
        }

#undef LOADROW
#undef ROWC
    }

    // partials -> LDS (padded stride, conflict-free)
    float* myp = &part[(w * 64 + lane) * LDSTRIDE];
#pragma unroll
    for (int j = 0; j < NCLS; ++j) myp[j] = acc[j];
    __syncthreads();

    // combine 8 partials + bias; coalesced 640-float store per block
    const int base = blockIdx.x * 64;
    for (int o = threadIdx.x; o < 64 * NCLS; o += THREADS) {
        const int im = o / NCLS;
        const int c  = o - im * NCLS;
        float s = bp[c];
#pragma unroll
        for (int w2 = 0; w2 < NW; ++w2)
            s += part[(w2 * 64 + im) * LDSTRIDE + c];
        if (base + im < B)
            out[(size_t)(base + im) * NCLS + c] = s;
    }
}

extern "C" void kernel_launch(void* const* d_in, const int* in_sizes, int n_in,
                              void* d_out, int out_size, void* d_ws, size_t ws_size,
                              hipStream_t stream) {
    const float* x  = (const float*)d_in[0];
    const float* cw = (const float*)d_in[1];
    const float* Wp = (const float*)d_in[2];
    const float* bp = (const float*)d_in[3];
    float* out = (float*)d_out;

    const int B = in_sizes[0] / (IMGD * IMGD);   // 32768
    const int grid = (B + 63) / 64;              // 512 blocks x 8 waves

    fused_conv_relu_fc<<<grid, THREADS, 0, stream>>>(x, cw, Wp, bp, out, B);
}

// Round 3
// 42.445 us; speedup vs baseline: 1.4388x; 1.0163x over previous
//
#include <hip/hip_runtime.h>

#define IMGD 28
#define OUTD 26
#define NCLS 10
#define NWAVE 16               // 2 row-halves x 8 col-strips
#define THREADS (NWAVE * 64)
#define LDSTRIDE 11            // pad 10 -> 11, conflict-free LDS combine

typedef float v2f __attribute__((ext_vector_type(2)));

// One image per lane; W / conv-tap addresses are wave-uniform -> s_load
// broadcasts. Each wave owns a 13-row x {4|2}-col output strip, streaming its
// input cols through a rolling 3x(W+2) register window (all static indices).
template <int WID>
__device__ __forceinline__ void strip_work(const float* __restrict__ xi,
                                           const float* __restrict__ Wp,
                                           const float* __restrict__ k,
                                           int c0, int r0, v2f* acc)
{
    float A[WID + 2], Bv[WID + 2], C[WID + 2];

#define LOADR(dst, r) do {                                              \
        const float* __restrict__ p = xi + (r) * IMGD + c0;             \
        if constexpr (WID == 4) {                                       \
            float4 a = *(const float4*)p;                               \
            float2 b = *(const float2*)(p + 4);                         \
            (dst)[0] = a.x; (dst)[1] = a.y; (dst)[2] = a.z;             \
            (dst)[3] = a.w; (dst)[4] = b.x; (dst)[5] = b.y;             \
        } else {                                                        \
            float2 a = *(const float2*)p;                               \
            float2 b = *(const float2*)(p + 2);                         \
            (dst)[0] = a.x; (dst)[1] = a.y;                             \
            (dst)[2] = b.x; (dst)[3] = b.y;                             \
        }                                                               \
    } while (0)

#define ROWC(r, X, Y, Z) do {                                           \
        _Pragma("unroll")                                               \
        for (int c = 0; c < WID; ++c) {                                 \
            float p0 = fmaf((X)[c], k[0], (X)[c+1] * k[1]);             \
            p0 = fmaf((X)[c+2], k[2], p0);                              \
            float p1 = fmaf((Y)[c], k[3], (Y)[c+1] * k[4]);             \
            p1 = fmaf((Y)[c+2], k[5], p1);                              \
            float p2 = fmaf((Z)[c], k[6], (Z)[c+1] * k[7]);             \
            p2 = fmaf((Z)[c+2], k[8], p2);                              \
            float v = fmaxf((p0 + p1) + p2, 0.0f);                      \
            const float* __restrict__ wr =                              \
                Wp + (size_t)((r) * OUTD + c0 + c) * NCLS;              \
            _Pragma("unroll")                                           \
            for (int p = 0; p < 5; ++p) {                               \
                v2f wv = *(const v2f*)(wr + 2 * p);                     \
                v2f vv; vv[0] = v; vv[1] = v;                           \
                acc[p] += vv * wv;   /* v_pk_fma_f32 */                 \
            }                                                           \
        }                                                               \
    } while (0)

    LOADR(A,  r0 + 0);
    LOADR(Bv, r0 + 1);
    LOADR(C,  r0 + 2);

#pragma unroll
    for (int t = 0; t < 4; ++t) {
        const int r = r0 + 3 * t;
        ROWC(r + 0, A, Bv, C);   LOADR(A,  r + 3);
        ROWC(r + 1, Bv, C, A);   LOADR(Bv, r + 4);
        ROWC(r + 2, C, A, Bv);   LOADR(C,  r + 5);
    }
    ROWC(r0 + 12, A, Bv, C);     // 13th row; uses input rows r0+12..r0+14

#undef LOADR
#undef ROWC
}

__global__ __launch_bounds__(THREADS, 8) void fused_conv_relu_fc(
    const float* __restrict__ x,      // [B, 784]
    const float* __restrict__ cw,     // [9]
    const float* __restrict__ Wp,     // [676, 10]
    const float* __restrict__ bp,     // [10]
    float* __restrict__ out,          // [B, 10]
    int B)
{
    __shared__ float part[NWAVE * 64 * LDSTRIDE];   // 44 KiB

    const int lane = threadIdx.x & 63;
    const int wv   = __builtin_amdgcn_readfirstlane((int)(threadIdx.x >> 6));
    const int img  = blockIdx.x * 64 + lane;

    const int rh = wv >> 3;          // row half: 0 -> rows 0..12, 1 -> 13..25
    const int cs = wv & 7;           // col strip: widths {4,4,4,4,4,2,2,2}
    const int r0 = rh * 13;

    float k[9];
#pragma unroll
    for (int i = 0; i < 9; ++i) k[i] = cw[i];

    v2f acc[5];
#pragma unroll
    for (int p = 0; p < 5; ++p) { acc[p][0] = 0.0f; acc[p][1] = 0.0f; }

    if (img < B) {
        const float* __restrict__ xi = x + (size_t)img * (IMGD * IMGD);
        if (cs < 5) strip_work<4>(xi, Wp, k, 4 * cs,            r0, acc);
        else        strip_work<2>(xi, Wp, k, 20 + 2 * (cs - 5), r0, acc);
    }

    // partials -> LDS (padded stride: conflict-free)
    float* myp = &part[(wv * 64 + lane) * LDSTRIDE];
#pragma unroll
    for (int p = 0; p < 5; ++p) {
        myp[2 * p + 0] = acc[p][0];
        myp[2 * p + 1] = acc[p][1];
    }
    __syncthreads();

    // combine 16 partials + bias; coalesced 640-float store per block
    const int base = blockIdx.x * 64;
    const int o = threadIdx.x;
    if (o < 64 * NCLS) {
        const int im = o / NCLS;
        const int c  = o - im * NCLS;
        float s = bp[c];
#pragma unroll
        for (int w2 = 0; w2 < NWAVE; ++w2)
            s += part[(w2 * 64 + im) * LDSTRIDE + c];
        if (base + im < B)
            out[(size_t)(base + im) * NCLS + c] = s;
    }
}

extern "C" void kernel_launch(void* const* d_in, const int* in_sizes, int n_in,
                              void* d_out, int out_size, void* d_ws, size_t ws_size,
                              hipStream_t stream) {
    const float* x  = (const float*)d_in[0];
    const float* cw = (const float*)d_in[1];
    const float* Wp = (const float*)d_in[2];
    const float* bp = (const float*)d_in[3];
    float* out = (float*)d_out;

    const int B = in_sizes[0] / (IMGD * IMGD);   // 32768
    const int grid = (B + 63) / 64;              // 512 blocks x 16 waves

    fused_conv_relu_fc<<<grid, THREADS, 0, stream>>>(x, cw, Wp, bp, out, B);
}

// Round 4
// 37.832 us; speedup vs baseline: 1.6142x; 1.1219x over previous
//
#include <hip/hip_runtime.h>

#define IMGD 28
#define OUTD 26
#define NCLS 10
#define NIMG 64                    // images per block (= lane)
#define BROWS 8                    // input rows per band
#define BUNITS 56                  // float4 units per image per band (8*28/4)
#define BWORDS (NIMG * BROWS * IMGD)   // 14336 floats per band buffer
#define THREADS 1024
#define LDSTRIDE 11

typedef float v2f __attribute__((ext_vector_type(2)));

// async global->LDS, 16B per lane; LDS dest is wave-uniform base + lane*16
__device__ __forceinline__ void gload_lds16(const float* gp, float* lp) {
    __builtin_amdgcn_global_load_lds(
        (const __attribute__((address_space(1))) void*)gp,
        (__attribute__((address_space(3))) void*)lp, 16, 0, 0);
}

// Stage one 8-row band of 64 images into LDS.
// LDS layout: [img][slot] in float4 units, slot = global_unit ^ (img&7)
// (inverse-swizzled SOURCE + linear dest; reads apply the same XOR).
// Per-lane global addresses are contiguous within each image's 896B chunk
// -> ~16 lines per wave-instr (vs 64 scattered).
__device__ __forceinline__ void stage_band(const float* __restrict__ x,
                                           int img_base, int B, int r0,
                                           float* buf, int wv, int lane)
{
#pragma unroll
    for (int it = 0; it < 4; ++it) {
        const int fw = it * 16 + wv;          // wave-uniform
        if (fw < 56) {
            const int f = fw * 64 + lane;     // flat float4 index 0..3583
            const int g = f / 56;             // image 0..63
            const int s = f - g * 56;         // LDS slot
            const int q = s ^ (g & 7);        // global unit (XOR involution)
            int gi = img_base + g; if (gi >= B) gi = B - 1;
            const float* gp = x + (size_t)gi * (IMGD * IMGD) + r0 * IMGD + q * 4;
            gload_lds16(gp, buf + fw * 256);  // uniform base; +lane*16B implicit
        }
    }
}

// Compute 3 (or 2) output rows x WID cols for this wave's strip, lane = image.
// Reads ds_read_b128 at lane*56 + (u ^ (lane&7)): 8 bank-groups -> conflict-free.
template<int WID, int NU, int OFF>
__device__ __forceinline__ void strip_compute(
    const float* buf, int lane, int u_col, int li, int nout,
    int wrow0, int c0, const float (&kk)[9],
    const float* __restrict__ Wp, v2f* acc)
{
    const float4* b4 = (const float4*)buf;
    const int sw = lane & 7;
    float R[5][4 * NU];
#pragma unroll
    for (int i = 0; i < 5; ++i) {
        if (i < nout + 2) {
            const int u = (li + i) * 7 + u_col;
            float4 a = b4[lane * 56 + (u ^ sw)];
            R[i][0] = a.x; R[i][1] = a.y; R[i][2] = a.z; R[i][3] = a.w;
            if (NU == 2) {
                float4 c = b4[lane * 56 + ((u + 1) ^ sw)];
                R[i][4] = c.x; R[i][5] = c.y; R[i][6] = c.z; R[i][7] = c.w;
            }
        }
    }
#pragma unroll
    for (int o = 0; o < 3; ++o) {
        if (o < nout) {
            const float *X = R[o], *Y = R[o + 1], *Z = R[o + 2];
#pragma unroll
            for (int c = 0; c < WID; ++c) {
                float p0 = fmaf(X[OFF+c], kk[0], X[OFF+c+1] * kk[1]);
                p0 = fmaf(X[OFF+c+2], kk[2], p0);
                float p1 = fmaf(Y[OFF+c], kk[3], Y[OFF+c+1] * kk[4]);
                p1 = fmaf(Y[OFF+c+2], kk[5], p1);
                float p2 = fmaf(Z[OFF+c], kk[6], Z[OFF+c+1] * kk[7]);
                p2 = fmaf(Z[OFF+c+2], kk[8], p2);
                float v = fmaxf((p0 + p1) + p2, 0.0f);
                // wave-uniform W address -> s_load broadcasts
                const float* wr = Wp + ((size_t)(wrow0 + o) * OUTD + (c0 + c)) * NCLS;
#pragma unroll
                for (int p = 0; p < 5; ++p) {
                    v2f wvv = *(const v2f*)(wr + 2 * p);
                    v2f vv; vv[0] = v; vv[1] = v;
                    acc[p] += vv * wvv;
                }
            }
        }
    }
}

__global__ __launch_bounds__(THREADS) void fused_conv_relu_fc(
    const float* __restrict__ x,      // [B, 784]
    const float* __restrict__ cw,     // [9]
    const float* __restrict__ Wp,     // [676, 10]
    const float* __restrict__ bp,     // [10]
    float* __restrict__ out,          // [B, 10]
    int B)
{
    __shared__ float lds[2 * BWORDS];     // 114688 B, double-buffered bands

    const int lane = threadIdx.x & 63;
    const int wv   = __builtin_amdgcn_readfirstlane((int)(threadIdx.x >> 6));
    const int rg   = wv >> 3;             // row-group (3 output rows)
    const int cs   = wv & 7;              // col strip
    const int img_base = blockIdx.x * NIMG;

    float kk[9];
#pragma unroll
    for (int i = 0; i < 9; ++i) kk[i] = cw[i];

    v2f acc[5];
#pragma unroll
    for (int p = 0; p < 5; ++p) { acc[p][0] = 0.0f; acc[p][1] = 0.0f; }

    // prologue: stage band 0
    stage_band(x, img_base, B, 0, lds, wv, lane);
    asm volatile("s_waitcnt vmcnt(0)" ::: "memory");
    __syncthreads();

    // bands: input rows r0 = 0,6,12,18,20 ; output rows 0-5,6-11,12-17,18-23,24-25
    for (int b = 0; b < 5; ++b) {
        if (b < 4) {
            const int r0n = (b + 1 < 4) ? 6 * (b + 1) : 20;
            stage_band(x, img_base, B, r0n, lds + ((b + 1) & 1) * BWORDS, wv, lane);
        }
        const float* buf = lds + (b & 1) * BWORDS;
        int nout, li, wrow0;
        if (b < 4) { nout = 3; li = rg * 3; wrow0 = 6 * b + rg * 3; }
        else       { nout = (rg == 0) ? 2 : 0; li = 4; wrow0 = 24; }
        if (nout) {
            if      (cs < 5)  strip_compute<4,2,0>(buf, lane, cs, li, nout, wrow0, 4*cs, kk, Wp, acc);
            else if (cs == 5) strip_compute<2,1,0>(buf, lane, 5,  li, nout, wrow0, 20,   kk, Wp, acc);
            else if (cs == 6) strip_compute<2,2,2>(buf, lane, 5,  li, nout, wrow0, 22,   kk, Wp, acc);
            else              strip_compute<2,1,0>(buf, lane, 6,  li, nout, wrow0, 24,   kk, Wp, acc);
        }
        asm volatile("s_waitcnt vmcnt(0)" ::: "memory");
        __syncthreads();
    }

    // combine: overlay partials on band buffer 0 (all reads completed above)
    float* part = lds;                    // 16*64*11 = 11264 floats
    float* myp = &part[(wv * 64 + lane) * LDSTRIDE];
#pragma unroll
    for (int p = 0; p < 5; ++p) { myp[2*p] = acc[p][0]; myp[2*p+1] = acc[p][1]; }
    __syncthreads();

    const int o = threadIdx.x;
    if (o < NIMG * NCLS) {
        const int im = o / NCLS;
        const int c  = o - im * NCLS;
        float s = bp[c];
#pragma unroll
        for (int w2 = 0; w2 < 16; ++w2)
            s += part[(w2 * 64 + im) * LDSTRIDE + c];
        if (img_base + im < B)
            out[(size_t)(img_base + im) * NCLS + c] = s;
    }
}

extern "C" void kernel_launch(void* const* d_in, const int* in_sizes, int n_in,
                              void* d_out, int out_size, void* d_ws, size_t ws_size,
                              hipStream_t stream) {
    const float* x  = (const float*)d_in[0];
    const float* cw = (const float*)d_in[1];
    const float* Wp = (const float*)d_in[2];
    const float* bp = (const float*)d_in[3];
    float* out = (float*)d_out;

    const int B = in_sizes[0] / (IMGD * IMGD);   // 32768
    const int grid = (B + NIMG - 1) / NIMG;      // 512 blocks x 16 waves

    fused_conv_relu_fc<<<grid, THREADS, 0, stream>>>(x, cw, Wp, bp, out, B);
}

// Round 5
// 32.549 us; speedup vs baseline: 1.8762x; 1.1623x over previous
//
#include <hip/hip_runtime.h>

#define IMGD 28
#define OUTD 26
#define NCLS 10
#define NIMG 64
#define UPB 29                       // padded float4 units per image per band (28 data + 1 pad)
#define BWORDS (NIMG * UPB * 4)      // 7424 floats = 29696 B per buffer
#define NBAND 7
#define THREADS 1024
#define LDSTRIDE 11

typedef float v2f __attribute__((ext_vector_type(2)));

__device__ __forceinline__ void gload_lds16(const float* gp, float* lp) {
    __builtin_amdgcn_global_load_lds(
        (const __attribute__((address_space(1))) void*)gp,
        (__attribute__((address_space(3))) void*)lp, 16, 0, 0);
}

// Stage one disjoint 4-row band (input rows r0..r0+3) of 64 images into buf.
// LDS layout: [img][unit], unit stride UPB=29 (odd) -> ds_read_b128 group
// (29*img + u) % 8 covers all 8 bank-quads across lanes: conflict-free.
// Source addresses are linear within each image's 448B row-block -> coalesced.
__device__ __forceinline__ void stage_band(const float* __restrict__ x,
                                           int img_base, int B, int r0,
                                           float* buf, int wv, int lane)
{
#pragma unroll
    for (int it = 0; it < 2; ++it) {
        const int fw = it * 16 + wv;             // wave-uniform chunk id
        if (fw < UPB) {
            const int f = fw * 64 + lane;        // flat unit 0..1855
            const int g = f / UPB;               // image 0..63
            const int s = f - g * UPB;           // LDS unit slot 0..28
            const int q = (s == 28) ? 27 : s;    // pad slot -> dup (same 64B line)
            int gi = img_base + g; if (gi >= B) gi = B - 1;
            const float* gp = x + (size_t)gi * (IMGD * IMGD) + r0 * IMGD + q * 4;
            gload_lds16(gp, buf + fw * 256);     // uniform base + lane*16B
        }
    }
}

// read NU float4 units (band row br, unit col u0) of image `lane`
template<int NU>
__device__ __forceinline__ void read_row(const float* buf, int lane, int br, int u0,
                                         float* dst)
{
    const float4* b4 = (const float4*)buf;
#pragma unroll
    for (int u = 0; u < NU; ++u) {
        float4 a = b4[lane * UPB + br * 7 + u0 + u];
        dst[4*u+0] = a.x; dst[4*u+1] = a.y; dst[4*u+2] = a.z; dst[4*u+3] = a.w;
    }
}

// one output row: conv3x3 (tree) + relu + rank-1 GEMM update, W wave-uniform
template<int WID, int OFF>
__device__ __forceinline__ void conv_row(const float* X, const float* Y, const float* Z,
                                         const float (&kk)[9],
                                         const float* __restrict__ wr, v2f* acc)
{
#pragma unroll
    for (int c = 0; c < WID; ++c) {
        float p0 = fmaf(X[OFF+c], kk[0], X[OFF+c+1] * kk[1]);
        p0 = fmaf(X[OFF+c+2], kk[2], p0);
        float p1 = fmaf(Y[OFF+c], kk[3], Y[OFF+c+1] * kk[4]);
        p1 = fmaf(Y[OFF+c+2], kk[5], p1);
        float p2 = fmaf(Z[OFF+c], kk[6], Z[OFF+c+1] * kk[7]);
        p2 = fmaf(Z[OFF+c+2], kk[8], p2);
        float v = fmaxf((p0 + p1) + p2, 0.0f);
        const float* w = wr + c * NCLS;          // wave-uniform -> s_load
#pragma unroll
        for (int p = 0; p < 5; ++p) {
            v2f wv2 = *(const v2f*)(w + 2 * p);
            v2f vv; vv[0] = v; vv[1] = v;
            acc[p] += vv * wv2;                  // v_pk_fma_f32
        }
    }
}

// Full band pipeline for one wave's strip. rg=0: 2 within-band output rows per
// phase. rg=1: 2 straddle rows (register-saved halo + next band) per phase.
template<int WID, int NU, int OFF>
__device__ __forceinline__ void run_all(
    const float* __restrict__ x, int img_base, int B,
    float* lds0, int wv, int lane, int rg, int u0, int c0,
    const float* __restrict__ cw, const float* __restrict__ Wp, v2f* acc)
{
    float kk[9];
#pragma unroll
    for (int i = 0; i < 9; ++i) kk[i] = cw[i];   // uniform -> SGPRs

    float S[2][4 * NU];                          // halo rows (rg=1 only)

    stage_band(x, img_base, B, 0, lds0,          wv, lane);
    stage_band(x, img_base, B, 4, lds0 + BWORDS, wv, lane);

    for (int k = 0; k < NBAND; ++k) {
        // wait band k; leave band k+1's loads in flight (counted vmcnt)
        if (k < NBAND - 1) {
            if (wv < 13) asm volatile("s_waitcnt vmcnt(2)" ::: "memory");
            else         asm volatile("s_waitcnt vmcnt(1)" ::: "memory");
        } else {
            asm volatile("s_waitcnt vmcnt(0)" ::: "memory");
        }
        __builtin_amdgcn_s_barrier();

        const float* buf = lds0 + (k & 1) * BWORDS;

        if (rg == 0) {
            // outputs r=4k, 4k+1 from band rows 0..3
            float R[4][4 * NU];
#pragma unroll
            for (int br = 0; br < 4; ++br) read_row<NU>(buf, lane, br, u0, R[br]);
            conv_row<WID, OFF>(R[0], R[1], R[2], kk,
                               Wp + ((size_t)(4 * k) * OUTD + c0) * NCLS, acc);
            conv_row<WID, OFF>(R[1], R[2], R[3], kk,
                               Wp + ((size_t)(4 * k + 1) * OUTD + c0) * NCLS, acc);
        } else {
            if (k > 0) {
                // straddle outputs r=4k-2, 4k-1: saved rows (4k-2,4k-1) + band k rows 0,1
                float T[2][4 * NU];
                read_row<NU>(buf, lane, 0, u0, T[0]);
                read_row<NU>(buf, lane, 1, u0, T[1]);
                conv_row<WID, OFF>(S[0], S[1], T[0], kk,
                                   Wp + ((size_t)(4 * k - 2) * OUTD + c0) * NCLS, acc);
                conv_row<WID, OFF>(S[1], T[0], T[1], kk,
                                   Wp + ((size_t)(4 * k - 1) * OUTD + c0) * NCLS, acc);
            }
            if (k < NBAND - 1) {                 // save halo before buffer recycled
                read_row<NU>(buf, lane, 2, u0, S[0]);
                read_row<NU>(buf, lane, 3, u0, S[1]);
            }
        }

        asm volatile("" ::: "memory");
        __builtin_amdgcn_s_barrier();            // all reads of buf[k&1] done
        asm volatile("" ::: "memory");

        if (k + 2 < NBAND)                        // recycle buf[k&1] for band k+2
            stage_band(x, img_base, B, 4 * (k + 2), lds0 + (k & 1) * BWORDS, wv, lane);
    }
}

__global__ __launch_bounds__(THREADS, 8) void fused_conv_relu_fc(
    const float* __restrict__ x,      // [B, 784]
    const float* __restrict__ cw,     // [9]
    const float* __restrict__ Wp,     // [676, 10]
    const float* __restrict__ bp,     // [10]
    float* __restrict__ out,          // [B, 10]
    int B)
{
    __shared__ float lds[2 * BWORDS];            // 59392 B -> 2 blocks/CU

    const int lane = threadIdx.x & 63;
    const int wv   = __builtin_amdgcn_readfirstlane((int)(threadIdx.x >> 6));
    const int rg   = wv >> 3;                    // 0: within-band, 1: straddle
    const int cs   = wv & 7;                     // col strip
    const int img_base = blockIdx.x * NIMG;

    v2f acc[5];
#pragma unroll
    for (int p = 0; p < 5; ++p) { acc[p][0] = 0.0f; acc[p][1] = 0.0f; }

    // strips: 5 x width-4 + 3 x width-2 (all barrier sequences identical)
    if      (cs < 5)  run_all<4,2,0>(x, img_base, B, lds, wv, lane, rg, cs, 4*cs, cw, Wp, acc);
    else if (cs == 5) run_all<2,1,0>(x, img_base, B, lds, wv, lane, rg, 5,  20,   cw, Wp, acc);
    else if (cs == 6) run_all<2,2,2>(x, img_base, B, lds, wv, lane, rg, 5,  22,   cw, Wp, acc);
    else              run_all<2,1,0>(x, img_base, B, lds, wv, lane, rg, 6,  24,   cw, Wp, acc);

    __syncthreads();                             // full drain before overlay

    // partials -> LDS overlay (stride 11: 2 lanes/bank -> free)
    float* part = lds;                           // 16*64*11*4 = 45056 B < 59392
    float* myp = &part[(wv * 64 + lane) * LDSTRIDE];
#pragma unroll
    for (int p = 0; p < 5; ++p) { myp[2*p] = acc[p][0]; myp[2*p+1] = acc[p][1]; }
    __syncthreads();

    // combine 16 partials + bias; coalesced 640-float store per block
    const int o = threadIdx.x;
    if (o < NIMG * NCLS) {
        const int im = o / NCLS;
        const int c  = o - im * NCLS;
        float s = bp[c];
#pragma unroll
        for (int w2 = 0; w2 < 16; ++w2)
            s += part[(w2 * 64 + im) * LDSTRIDE + c];
        if (img_base + im < B)
            out[(size_t)(img_base + im) * NCLS + c] = s;
    }
}

extern "C" void kernel_launch(void* const* d_in, const int* in_sizes, int n_in,
                              void* d_out, int out_size, void* d_ws, size_t ws_size,
                              hipStream_t stream) {
    const float* x  = (const float*)d_in[0];
    const float* cw = (const float*)d_in[1];
    const float* Wp = (const float*)d_in[2];
    const float* bp = (const float*)d_in[3];
    float* out = (float*)d_out;

    const int B = in_sizes[0] / (IMGD * IMGD);   // 32768
    const int grid = (B + NIMG - 1) / NIMG;      // 512 blocks x 16 waves

    fused_conv_relu_fc<<<grid, THREADS, 0, stream>>>(x, cw, Wp, bp, out, B);
}